// Round 1
// baseline (43669.727 us; speedup 1.0000x reference)
//
#include <hip/hip_runtime.h>
#include <hip/hip_bf16.h>
#include <math.h>

// ---------------- problem constants ----------------
#define S_LEN 2048
#define T_LEN 2048
#define HID   1024
#define GATES 4096          // 4*HID
#define VOCAB 50257
#define NWG   64            // persistent-RNN workgroups
#define RECT  512           // threads per rec workgroup

__device__ __forceinline__ float sigmoidf_(float x) { return 1.0f / (1.0f + expf(-x)); }

// ---------------- tiny helpers ----------------
__global__ void zero_f32(float* __restrict__ p, int n) {
  int i = blockIdx.x * blockDim.x + threadIdx.x;
  if (i < n) p[i] = 0.0f;
}

__global__ void build_dec_tokens(const int* __restrict__ outputs, const int* __restrict__ sos,
                                 int* __restrict__ toks, int T) {
  int t = blockIdx.x * blockDim.x + threadIdx.x;
  if (t < T) toks[t] = (t == 0) ? sos[0] : outputs[t - 1];
}

// one block per row; 256 threads copy 1024 floats as float4
__global__ void gather_rows(const float* __restrict__ emb, const int* __restrict__ toks,
                            float* __restrict__ out) {
  int row = blockIdx.x;
  int tok = toks[row];
  const float4* src = (const float4*)(emb + (size_t)tok * HID);
  float4* dst = (float4*)(out + (size_t)row * HID);
  dst[threadIdx.x] = src[threadIdx.x];
}

// ---------------- f32 GEMM: C[M][N] = X[M][K] @ W[N][K]^T + b1 + b2 ----------------
// 64x64 tile, 256 threads, 4x4 microtile, BK=16
__global__ __launch_bounds__(256) void gemm_xwt(
    const float* __restrict__ X, const float* __restrict__ W,
    const float* __restrict__ b1, const float* __restrict__ b2,
    float* __restrict__ C, int M, int N, int K)
{
  __shared__ float Xs[16][68];   // [k][m], padded
  __shared__ float Ws[16][68];   // [k][n]
  const int tid = threadIdx.x;
  const int tx = tid & 15;
  const int ty = tid >> 4;
  const int m0 = blockIdx.y * 64;
  const int n0 = blockIdx.x * 64;
  const int lr = tid >> 2;          // 0..63 tile row
  const int lc = (tid & 3) * 4;     // 0,4,8,12 k offset
  float acc[4][4] = {{0.f}};

  for (int k0 = 0; k0 < K; k0 += 16) {
    float4 xv = *(const float4*)(X + (size_t)(m0 + lr) * K + k0 + lc);
    float4 wv = make_float4(0.f, 0.f, 0.f, 0.f);
    int wr = n0 + lr;
    if (wr < N) wv = *(const float4*)(W + (size_t)wr * K + k0 + lc);
    __syncthreads();
    Xs[lc + 0][lr] = xv.x; Xs[lc + 1][lr] = xv.y; Xs[lc + 2][lr] = xv.z; Xs[lc + 3][lr] = xv.w;
    Ws[lc + 0][lr] = wv.x; Ws[lc + 1][lr] = wv.y; Ws[lc + 2][lr] = wv.z; Ws[lc + 3][lr] = wv.w;
    __syncthreads();
#pragma unroll
    for (int kk = 0; kk < 16; ++kk) {
      float4 a = *(const float4*)&Xs[kk][ty * 4];
      float4 b = *(const float4*)&Ws[kk][tx * 4];
      float av[4] = {a.x, a.y, a.z, a.w};
      float bv[4] = {b.x, b.y, b.z, b.w};
#pragma unroll
      for (int i = 0; i < 4; ++i)
#pragma unroll
        for (int j = 0; j < 4; ++j)
          acc[i][j] = fmaf(av[i], bv[j], acc[i][j]);
    }
  }
#pragma unroll
  for (int i = 0; i < 4; ++i) {
    int m = m0 + ty * 4 + i;
#pragma unroll
    for (int j = 0; j < 4; ++j) {
      int n = n0 + tx * 4 + j;
      if (n < N) {
        float bias = 0.f;
        if (b1) bias += b1[n];
        if (b2) bias += b2[n];
        C[(size_t)m * N + n] = acc[i][j] + bias;
      }
    }
  }
}

// ---------------- persistent LSTM recurrence ----------------
// A[t][4096] = Wi@x_t + bi + bh (precomputed). This kernel adds Wh@h_{t-1},
// applies gates, and runs all T steps with a grid-wide barrier per step.
// 64 wgs x 512 threads; each wg owns 16 hidden units j (64 gate-rows);
// 8 lanes per row; each thread's 128 Whh weights live in registers.
__global__ __launch_bounds__(RECT, 2) void lstm_rec(
    const float* __restrict__ A, const float* __restrict__ Whh,
    const float* __restrict__ h0, const float* __restrict__ c0,
    float* __restrict__ Hseq,        // [T][HID] or nullptr
    float* __restrict__ hfin,        // [HID] or nullptr
    float* __restrict__ cfin,        // [HID] or nullptr
    float* __restrict__ hbuf,        // [2][HID] ping-pong exchange
    int* __restrict__ arrive,        // [NWG], zeroed before launch
    int T)
{
  const int tid = threadIdx.x;
  const int wg = blockIdx.x;
  const int lane8 = tid & 7;
  const int rloc = tid >> 3;            // 0..63 local row
  const int jloc = rloc & 15;           // hidden unit within wg
  const int gate = rloc >> 4;           // 0=i 1=f 2=g 3=o (PyTorch order)
  const int grow = gate * HID + wg * 16 + jloc;   // row in [0,4096)

  __shared__ float lds_h[HID];
  __shared__ float lds_g[64];
  __shared__ float lds_c[16];

  // Whh row chunk -> registers: cols {lane8*4 + 32*i + e}
  float4 Wr[32];
  {
    const float4* wrow = (const float4*)(Whh + (size_t)grow * HID);
#pragma unroll
    for (int i = 0; i < 32; ++i) Wr[i] = wrow[lane8 + i * 8];
  }

  if (tid < 16) lds_c[tid] = c0[wg * 16 + tid];
  if (tid < 256) ((float4*)lds_h)[tid] = ((const float4*)h0)[tid];
  __syncthreads();

  for (int t = 0; t < T; ++t) {
    float aval = 0.f;
    if (lane8 == 0) aval = A[(size_t)t * GATES + grow];

    // recurrent dot: 128 MACs per thread, 4 chains
    float s0 = 0.f, s1 = 0.f, s2 = 0.f, s3 = 0.f;
#pragma unroll
    for (int i = 0; i < 32; ++i) {
      const float4 hv = *(const float4*)&lds_h[(lane8 << 2) + (i << 5)];
      s0 = fmaf(Wr[i].x, hv.x, s0);
      s1 = fmaf(Wr[i].y, hv.y, s1);
      s2 = fmaf(Wr[i].z, hv.z, s2);
      s3 = fmaf(Wr[i].w, hv.w, s3);
    }
    float sum = (s0 + s1) + (s2 + s3);
    sum += __shfl_xor(sum, 1);
    sum += __shfl_xor(sum, 2);
    sum += __shfl_xor(sum, 4);
    if (lane8 == 0) lds_g[rloc] = sum + aval;
    __syncthreads();

    if (tid < 16) {
      const int j = tid;
      const float gi = lds_g[j];
      const float gf = lds_g[16 + j];
      const float gg = lds_g[32 + j];
      const float go = lds_g[48 + j];
      const float c = sigmoidf_(gf) * lds_c[j] + sigmoidf_(gi) * tanhf(gg);
      const float h = sigmoidf_(go) * tanhf(c);
      lds_c[j] = c;
      const int col = wg * 16 + j;
      hbuf[(t & 1) * HID + col] = h;
      if (Hseq) Hseq[(size_t)t * HID + col] = h;
      if (t == T - 1) {
        if (hfin) hfin[col] = h;
        if (cfin) cfin[col] = c;
      }
    }
    __syncthreads();   // all global h-stores issued & drained (barrier implies vmcnt(0))

    // grid barrier: per-wg exclusive slot, monotonic count = t+1
    if (tid == 0)
      __hip_atomic_store(&arrive[wg], t + 1, __ATOMIC_RELEASE, __HIP_MEMORY_SCOPE_AGENT);
    if (tid < NWG) {
      while (__hip_atomic_load(&arrive[tid], __ATOMIC_ACQUIRE, __HIP_MEMORY_SCOPE_AGENT) <= t)
        __builtin_amdgcn_s_sleep(1);
    }
    __syncthreads();

    // stage h_t for next step
    if (tid < 256) ((float4*)lds_h)[tid] = ((const float4*)(hbuf + (t & 1) * HID))[tid];
    __syncthreads();
  }
}

// ---------------- launch ----------------
extern "C" void kernel_launch(void* const* d_in, const int* in_sizes, int n_in,
                              void* d_out, int out_size, void* d_ws, size_t ws_size,
                              hipStream_t stream) {
  const int*   inputs  = (const int*)d_in[0];
  const int*   outputs = (const int*)d_in[1];
  const int*   sos     = (const int*)d_in[2];
  const float* enc_emb = (const float*)d_in[3];
  const float* dec_emb = (const float*)d_in[4];
  const float* enc_Wih = (const float*)d_in[5];
  const float* enc_Whh = (const float*)d_in[6];
  const float* enc_bih = (const float*)d_in[7];
  const float* enc_bhh = (const float*)d_in[8];
  const float* dec_Wih = (const float*)d_in[9];
  const float* dec_Whh = (const float*)d_in[10];
  const float* dec_bih = (const float*)d_in[11];
  const float* dec_bhh = (const float*)d_in[12];
  const float* lin_W   = (const float*)d_in[13];
  const float* lin_b   = (const float*)d_in[14];

  char* ws = (char*)d_ws;
  int*   arrive  = (int*)(ws + 0);        // 4 phases x 64 ints
  float* zerosv  = (float*)(ws + 4096);   // 1024 zeros (h0/c0 for encoder)
  float* hfin_e0 = (float*)(ws + 8192);
  float* cfin_e0 = (float*)(ws + 12288);
  float* hfin_e1 = (float*)(ws + 16384);
  float* cfin_e1 = (float*)(ws + 20480);
  float* hbuf    = (float*)(ws + 24576);  // 2 x 1024 ping-pong
  int*   dtoks   = (int*)(ws + 32768);    // 2048 decoder tokens
  float* B1 = (float*)(ws + ((size_t)1  << 20));  // 8 MB: enc emb, later dec_out
  float* B2 = (float*)(ws + ((size_t)10 << 20));  // 8 MB: layer-0 h-sequences
  float* B3 = (float*)(ws + ((size_t)19 << 20));  // 8 MB: dec emb
  float* A  = (float*)d_out;                      // 32 MB gate-preactivations, scratch in d_out
  float* out = (float*)d_out;

  const size_t WOFF = (size_t)GATES * HID;  // layer stride in Wih/Whh
  const dim3 gemm_blk(256);
  const dim3 gemmA_grid(GATES / 64, S_LEN / 64);
  const dim3 gemmV_grid((VOCAB + 63) / 64, T_LEN / 64);

  // init small state (arrive counters + zeros vector)
  zero_f32<<<8, 256, 0, stream>>>((float*)ws, 2048);
  build_dec_tokens<<<8, 256, 0, stream>>>(outputs, sos, dtoks, T_LEN);

  // ---- encoder ----
  gather_rows<<<S_LEN, 256, 0, stream>>>(enc_emb, inputs, B1);
  gemm_xwt<<<gemmA_grid, gemm_blk, 0, stream>>>(B1, enc_Wih, enc_bih, enc_bhh, A, S_LEN, GATES, HID);
  lstm_rec<<<NWG, RECT, 0, stream>>>(A, enc_Whh, zerosv, zerosv, B2, hfin_e0, cfin_e0, hbuf, arrive + 0, S_LEN);
  gemm_xwt<<<gemmA_grid, gemm_blk, 0, stream>>>(B2, enc_Wih + WOFF, enc_bih + GATES, enc_bhh + GATES, A, S_LEN, GATES, HID);
  lstm_rec<<<NWG, RECT, 0, stream>>>(A, enc_Whh + WOFF, zerosv, zerosv, nullptr, hfin_e1, cfin_e1, hbuf, arrive + 64, S_LEN);

  // ---- decoder ----
  gather_rows<<<T_LEN, 256, 0, stream>>>(dec_emb, dtoks, B3);
  gemm_xwt<<<gemmA_grid, gemm_blk, 0, stream>>>(B3, dec_Wih, dec_bih, dec_bhh, A, T_LEN, GATES, HID);
  lstm_rec<<<NWG, RECT, 0, stream>>>(A, dec_Whh, hfin_e0, cfin_e0, B2, nullptr, nullptr, hbuf, arrive + 128, T_LEN);
  gemm_xwt<<<gemmA_grid, gemm_blk, 0, stream>>>(B2, dec_Wih + WOFF, dec_bih + GATES, dec_bhh + GATES, A, T_LEN, GATES, HID);
  lstm_rec<<<NWG, RECT, 0, stream>>>(A, dec_Whh + WOFF, hfin_e1, cfin_e1, B1, nullptr, nullptr, hbuf, arrive + 192, T_LEN);

  // ---- logits ----
  gemm_xwt<<<gemmV_grid, gemm_blk, 0, stream>>>(B1, lin_W, lin_b, nullptr, out, T_LEN, VOCAB, HID);
}

// Round 2
// 20767.725 us; speedup vs baseline: 2.1028x; 2.1028x over previous
//
#include <hip/hip_runtime.h>
#include <hip/hip_bf16.h>
#include <math.h>

// ---------------- problem constants ----------------
#define S_LEN 2048
#define T_LEN 2048
#define HID   1024
#define GATES 4096          // 4*HID
#define VOCAB 50257
#define NWG   64            // persistent-RNN workgroups
#define RECT  512           // threads per rec workgroup

typedef unsigned long long ull;

__device__ __forceinline__ float sigmoidf_(float x) { return 1.0f / (1.0f + expf(-x)); }

// ---------------- tiny helpers ----------------
__global__ void zero_f32(float* __restrict__ p, int n) {
  int i = blockIdx.x * blockDim.x + threadIdx.x;
  if (i < n) p[i] = 0.0f;
}

__global__ void build_dec_tokens(const int* __restrict__ outputs, const int* __restrict__ sos,
                                 int* __restrict__ toks, int T) {
  int t = blockIdx.x * blockDim.x + threadIdx.x;
  if (t < T) toks[t] = (t == 0) ? sos[0] : outputs[t - 1];
}

// one block per row; 256 threads copy 1024 floats as float4
__global__ void gather_rows(const float* __restrict__ emb, const int* __restrict__ toks,
                            float* __restrict__ out) {
  int row = blockIdx.x;
  int tok = toks[row];
  const float4* src = (const float4*)(emb + (size_t)tok * HID);
  float4* dst = (float4*)(out + (size_t)row * HID);
  dst[threadIdx.x] = src[threadIdx.x];
}

// ---------------- f32 GEMM: C[M][N] = X[M][K] @ W[N][K]^T + b1 + b2 ----------------
// 64x64 tile, 256 threads, 4x4 microtile, BK=16
__global__ __launch_bounds__(256) void gemm_xwt(
    const float* __restrict__ X, const float* __restrict__ W,
    const float* __restrict__ b1, const float* __restrict__ b2,
    float* __restrict__ C, int M, int N, int K)
{
  __shared__ float Xs[16][68];   // [k][m], padded
  __shared__ float Ws[16][68];   // [k][n]
  const int tid = threadIdx.x;
  const int tx = tid & 15;
  const int ty = tid >> 4;
  const int m0 = blockIdx.y * 64;
  const int n0 = blockIdx.x * 64;
  const int lr = tid >> 2;          // 0..63 tile row
  const int lc = (tid & 3) * 4;     // 0,4,8,12 k offset
  float acc[4][4] = {{0.f}};

  for (int k0 = 0; k0 < K; k0 += 16) {
    float4 xv = *(const float4*)(X + (size_t)(m0 + lr) * K + k0 + lc);
    float4 wv = make_float4(0.f, 0.f, 0.f, 0.f);
    int wr = n0 + lr;
    if (wr < N) wv = *(const float4*)(W + (size_t)wr * K + k0 + lc);
    __syncthreads();
    Xs[lc + 0][lr] = xv.x; Xs[lc + 1][lr] = xv.y; Xs[lc + 2][lr] = xv.z; Xs[lc + 3][lr] = xv.w;
    Ws[lc + 0][lr] = wv.x; Ws[lc + 1][lr] = wv.y; Ws[lc + 2][lr] = wv.z; Ws[lc + 3][lr] = wv.w;
    __syncthreads();
#pragma unroll
    for (int kk = 0; kk < 16; ++kk) {
      float4 a = *(const float4*)&Xs[kk][ty * 4];
      float4 b = *(const float4*)&Ws[kk][tx * 4];
      float av[4] = {a.x, a.y, a.z, a.w};
      float bv[4] = {b.x, b.y, b.z, b.w};
#pragma unroll
      for (int i = 0; i < 4; ++i)
#pragma unroll
        for (int j = 0; j < 4; ++j)
          acc[i][j] = fmaf(av[i], bv[j], acc[i][j]);
    }
  }
#pragma unroll
  for (int i = 0; i < 4; ++i) {
    int m = m0 + ty * 4 + i;
#pragma unroll
    for (int j = 0; j < 4; ++j) {
      int n = n0 + tx * 4 + j;
      if (n < N) {
        float bias = 0.f;
        if (b1) bias += b1[n];
        if (b2) bias += b2[n];
        C[(size_t)m * N + n] = acc[i][j] + bias;
      }
    }
  }
}

// ---------------- persistent LSTM recurrence, tagged-dataflow exchange ----------------
// A[t][4096] = Wi@x_t + bi + bh (precomputed by GEMM). Each of 64 WGs owns 16
// hidden units (64 gate rows, 8 lanes/row, 128 Whh weights in registers/thread).
// Cross-WG h exchange: each h is an 8-byte relaxed agent-scope atomic
// {tag = t+1 (hi32), h bits (lo32)} in a 2-deep ping-pong (slot buffer = t&1).
// Relaxed agent atomics are coherent past the non-coherent per-XCD L2 and emit
// NO cache-maintenance ops — no acquire/release, no grid barrier at all.
// 2-deep is overwrite-safe: a producer reaches step t+2 only after every WG
// consumed step t (data dependence through h_{t+1}).
__global__ __launch_bounds__(RECT, 2) void lstm_rec(
    const float* __restrict__ A, const float* __restrict__ Whh,
    const float* __restrict__ h0, const float* __restrict__ c0,
    float* __restrict__ Hseq,        // [T][HID] or nullptr
    float* __restrict__ hfin,        // [HID] or nullptr
    float* __restrict__ cfin,        // [HID] or nullptr
    ull* __restrict__ hslots,        // [2][HID] tagged slots, tags zeroed
    int T)
{
  const int tid = threadIdx.x;
  const int wg = blockIdx.x;
  const int lane8 = tid & 7;
  const int rloc = tid >> 3;            // 0..63 local row
  const int jloc = rloc & 15;           // hidden unit within wg
  const int gate = rloc >> 4;           // 0=i 1=f 2=g 3=o (PyTorch order)
  const int grow = gate * HID + wg * 16 + jloc;   // row in [0,4096)

  __shared__ float lds_h[HID];
  __shared__ float lds_g[64];
  __shared__ float lds_c[16];

  // Whh row chunk -> registers: cols {lane8*4 + 32*i + e}
  float4 Wr[32];
  {
    const float4* wrow = (const float4*)(Whh + (size_t)grow * HID);
#pragma unroll
    for (int i = 0; i < 32; ++i) Wr[i] = wrow[lane8 + i * 8];
  }

  if (tid < 16) lds_c[tid] = c0[wg * 16 + tid];
  if (tid < 256) ((float4*)lds_h)[tid] = ((const float4*)h0)[tid];
  __syncthreads();

  for (int t = 0; t < T; ++t) {
    if (t > 0) {
      // gather h_{t-1}: poll tagged slots (buffer (t-1)&1, want tag >= t)
      const ull* hb = hslots + (size_t)((t - 1) & 1) * HID;
      ull v0 = __hip_atomic_load(&hb[2 * tid],     __ATOMIC_RELAXED, __HIP_MEMORY_SCOPE_AGENT);
      ull v1 = __hip_atomic_load(&hb[2 * tid + 1], __ATOMIC_RELAXED, __HIP_MEMORY_SCOPE_AGENT);
      while ((unsigned)(v0 >> 32) < (unsigned)t)
        v0 = __hip_atomic_load(&hb[2 * tid],     __ATOMIC_RELAXED, __HIP_MEMORY_SCOPE_AGENT);
      while ((unsigned)(v1 >> 32) < (unsigned)t)
        v1 = __hip_atomic_load(&hb[2 * tid + 1], __ATOMIC_RELAXED, __HIP_MEMORY_SCOPE_AGENT);
      lds_h[2 * tid]     = __uint_as_float((unsigned)v0);
      lds_h[2 * tid + 1] = __uint_as_float((unsigned)v1);
      __syncthreads();
    }

    float aval = (lane8 == 0) ? A[(size_t)t * GATES + grow] : 0.f;

    // recurrent dot: 128 MACs per thread, 4 chains
    float s0 = 0.f, s1 = 0.f, s2 = 0.f, s3 = 0.f;
#pragma unroll
    for (int i = 0; i < 32; ++i) {
      const float4 hv = *(const float4*)&lds_h[(lane8 << 2) + (i << 5)];
      s0 = fmaf(Wr[i].x, hv.x, s0);
      s1 = fmaf(Wr[i].y, hv.y, s1);
      s2 = fmaf(Wr[i].z, hv.z, s2);
      s3 = fmaf(Wr[i].w, hv.w, s3);
    }
    float sum = (s0 + s1) + (s2 + s3);
    sum += __shfl_xor(sum, 1);
    sum += __shfl_xor(sum, 2);
    sum += __shfl_xor(sum, 4);
    if (lane8 == 0) lds_g[rloc] = sum + aval;
    __syncthreads();

    if (tid < 16) {
      const int j = tid;
      const float gi = lds_g[j];
      const float gf = lds_g[16 + j];
      const float gg = lds_g[32 + j];
      const float go = lds_g[48 + j];
      const float c = sigmoidf_(gf) * lds_c[j] + sigmoidf_(gi) * tanhf(gg);
      const float h = sigmoidf_(go) * tanhf(c);
      lds_c[j] = c;
      const int col = wg * 16 + j;
      const ull pk = ((ull)(unsigned)(t + 1) << 32) | (ull)__float_as_uint(h);
      __hip_atomic_store(&hslots[(size_t)(t & 1) * HID + col], pk,
                         __ATOMIC_RELAXED, __HIP_MEMORY_SCOPE_AGENT);
      if (Hseq) Hseq[(size_t)t * HID + col] = h;
      if (t == T - 1) {
        if (hfin) hfin[col] = h;
        if (cfin) cfin[col] = c;
      }
    }
    // no barrier: next iteration's staging sync orders lds_g/lds_h reuse
  }
}

// ---------------- launch ----------------
extern "C" void kernel_launch(void* const* d_in, const int* in_sizes, int n_in,
                              void* d_out, int out_size, void* d_ws, size_t ws_size,
                              hipStream_t stream) {
  const int*   inputs  = (const int*)d_in[0];
  const int*   outputs = (const int*)d_in[1];
  const int*   sos     = (const int*)d_in[2];
  const float* enc_emb = (const float*)d_in[3];
  const float* dec_emb = (const float*)d_in[4];
  const float* enc_Wih = (const float*)d_in[5];
  const float* enc_Whh = (const float*)d_in[6];
  const float* enc_bih = (const float*)d_in[7];
  const float* enc_bhh = (const float*)d_in[8];
  const float* dec_Wih = (const float*)d_in[9];
  const float* dec_Whh = (const float*)d_in[10];
  const float* dec_bih = (const float*)d_in[11];
  const float* dec_bhh = (const float*)d_in[12];
  const float* lin_W   = (const float*)d_in[13];
  const float* lin_b   = (const float*)d_in[14];

  char* ws = (char*)d_ws;
  ull*   hs      = (ull*)(ws + 0);        // 4 phases x 2 x 1024 x 8B = 64 KB tagged slots
  float* zerosv  = (float*)(ws + 65536);  // 1024 zeros (h0/c0 for encoder)
  float* hfin_e0 = (float*)(ws + 69632);
  float* cfin_e0 = (float*)(ws + 73728);
  float* hfin_e1 = (float*)(ws + 77824);
  float* cfin_e1 = (float*)(ws + 81920);
  int*   dtoks   = (int*)(ws + 86016);    // 2048 decoder tokens
  float* B1 = (float*)(ws + ((size_t)1  << 20));  // 8 MB: enc emb, later dec_out
  float* B2 = (float*)(ws + ((size_t)10 << 20));  // 8 MB: layer-0 h-sequences
  float* B3 = (float*)(ws + ((size_t)19 << 20));  // 8 MB: dec emb
  float* A  = (float*)d_out;                      // 32 MB gate-preactivations, scratch in d_out
  float* out = (float*)d_out;

  const size_t WOFF = (size_t)GATES * HID;  // layer stride in Wih/Whh
  const dim3 gemm_blk(256);
  const dim3 gemmA_grid(GATES / 64, S_LEN / 64);
  const dim3 gemmV_grid((VOCAB + 63) / 64, T_LEN / 64);

  // zero tagged slots (4 x 16 KB) + zeros vector: 17408 dwords from ws base
  zero_f32<<<68, 256, 0, stream>>>((float*)ws, 17408);
  build_dec_tokens<<<8, 256, 0, stream>>>(outputs, sos, dtoks, T_LEN);

  // ---- encoder ----
  gather_rows<<<S_LEN, 256, 0, stream>>>(enc_emb, inputs, B1);
  gemm_xwt<<<gemmA_grid, gemm_blk, 0, stream>>>(B1, enc_Wih, enc_bih, enc_bhh, A, S_LEN, GATES, HID);
  lstm_rec<<<NWG, RECT, 0, stream>>>(A, enc_Whh, zerosv, zerosv, B2, hfin_e0, cfin_e0, hs + 0 * 2048, S_LEN);
  gemm_xwt<<<gemmA_grid, gemm_blk, 0, stream>>>(B2, enc_Wih + WOFF, enc_bih + GATES, enc_bhh + GATES, A, S_LEN, GATES, HID);
  lstm_rec<<<NWG, RECT, 0, stream>>>(A, enc_Whh + WOFF, zerosv, zerosv, nullptr, hfin_e1, cfin_e1, hs + 1 * 2048, S_LEN);

  // ---- decoder ----
  gather_rows<<<T_LEN, 256, 0, stream>>>(dec_emb, dtoks, B3);
  gemm_xwt<<<gemmA_grid, gemm_blk, 0, stream>>>(B3, dec_Wih, dec_bih, dec_bhh, A, T_LEN, GATES, HID);
  lstm_rec<<<NWG, RECT, 0, stream>>>(A, dec_Whh, hfin_e0, cfin_e0, B2, nullptr, nullptr, hs + 2 * 2048, T_LEN);
  gemm_xwt<<<gemmA_grid, gemm_blk, 0, stream>>>(B2, dec_Wih + WOFF, dec_bih + GATES, dec_bhh + GATES, A, T_LEN, GATES, HID);
  lstm_rec<<<NWG, RECT, 0, stream>>>(A, dec_Whh + WOFF, hfin_e1, cfin_e1, B1, nullptr, nullptr, hs + 3 * 2048, T_LEN);

  // ---- logits ----
  gemm_xwt<<<gemmV_grid, gemm_blk, 0, stream>>>(B1, lin_W, lin_b, nullptr, out, T_LEN, VOCAB, HID);
}

// Round 3
// 13967.361 us; speedup vs baseline: 3.1266x; 1.4869x over previous
//
#include <hip/hip_runtime.h>
#include <hip/hip_bf16.h>
#include <math.h>

// ---------------- problem constants ----------------
#define S_LEN 2048
#define T_LEN 2048
#define HID   1024
#define GATES 4096          // 4*HID
#define VOCAB 50257
#define NWG2  192           // fused kernel: 64 L0 WGs + 128 L1 WGs
#define RECT  512           // threads per rec workgroup

typedef unsigned long long ull;

__device__ __forceinline__ float sigmoidf_(float x) { return 1.0f / (1.0f + expf(-x)); }

// ---------------- tiny helpers ----------------
__global__ void zero_f32(float* __restrict__ p, int n) {
  int i = blockIdx.x * blockDim.x + threadIdx.x;
  if (i < n) p[i] = 0.0f;
}

__global__ void zero_f4(float4* __restrict__ p, size_t n4) {
  size_t i = (size_t)blockIdx.x * blockDim.x + threadIdx.x;
  size_t stride = (size_t)gridDim.x * blockDim.x;
  for (; i < n4; i += stride) p[i] = make_float4(0.f, 0.f, 0.f, 0.f);
}

__global__ void build_dec_tokens(const int* __restrict__ outputs, const int* __restrict__ sos,
                                 int* __restrict__ toks, int T) {
  int t = blockIdx.x * blockDim.x + threadIdx.x;
  if (t < T) toks[t] = (t == 0) ? sos[0] : outputs[t - 1];
}

// one block per row; 256 threads copy 1024 floats as float4
__global__ void gather_rows(const float* __restrict__ emb, const int* __restrict__ toks,
                            float* __restrict__ out) {
  int row = blockIdx.x;
  int tok = toks[row];
  const float4* src = (const float4*)(emb + (size_t)tok * HID);
  float4* dst = (float4*)(out + (size_t)row * HID);
  dst[threadIdx.x] = src[threadIdx.x];
}

// ---------------- f32 GEMM: C[M][N] = X[M][K] @ W[N][K]^T + b1 + b2 ----------------
// 64x64 tile, 256 threads, 4x4 microtile, BK=16
__global__ __launch_bounds__(256) void gemm_xwt(
    const float* __restrict__ X, const float* __restrict__ W,
    const float* __restrict__ b1, const float* __restrict__ b2,
    float* __restrict__ C, int M, int N, int K)
{
  __shared__ float Xs[16][68];   // [k][m], padded
  __shared__ float Ws[16][68];   // [k][n]
  const int tid = threadIdx.x;
  const int tx = tid & 15;
  const int ty = tid >> 4;
  const int m0 = blockIdx.y * 64;
  const int n0 = blockIdx.x * 64;
  const int lr = tid >> 2;          // 0..63 tile row
  const int lc = (tid & 3) * 4;     // 0,4,8,12 k offset
  float acc[4][4] = {{0.f}};

  for (int k0 = 0; k0 < K; k0 += 16) {
    float4 xv = *(const float4*)(X + (size_t)(m0 + lr) * K + k0 + lc);
    float4 wv = make_float4(0.f, 0.f, 0.f, 0.f);
    int wr = n0 + lr;
    if (wr < N) wv = *(const float4*)(W + (size_t)wr * K + k0 + lc);
    __syncthreads();
    Xs[lc + 0][lr] = xv.x; Xs[lc + 1][lr] = xv.y; Xs[lc + 2][lr] = xv.z; Xs[lc + 3][lr] = xv.w;
    Ws[lc + 0][lr] = wv.x; Ws[lc + 1][lr] = wv.y; Ws[lc + 2][lr] = wv.z; Ws[lc + 3][lr] = wv.w;
    __syncthreads();
#pragma unroll
    for (int kk = 0; kk < 16; ++kk) {
      float4 a = *(const float4*)&Xs[kk][ty * 4];
      float4 b = *(const float4*)&Ws[kk][tx * 4];
      float av[4] = {a.x, a.y, a.z, a.w};
      float bv[4] = {b.x, b.y, b.z, b.w};
#pragma unroll
      for (int i = 0; i < 4; ++i)
#pragma unroll
        for (int j = 0; j < 4; ++j)
          acc[i][j] = fmaf(av[i], bv[j], acc[i][j]);
    }
  }
#pragma unroll
  for (int i = 0; i < 4; ++i) {
    int m = m0 + ty * 4 + i;
#pragma unroll
    for (int j = 0; j < 4; ++j) {
      int n = n0 + tx * 4 + j;
      if (n < N) {
        float bias = 0.f;
        if (b1) bias += b1[n];
        if (b2) bias += b2[n];
        C[(size_t)m * N + n] = acc[i][j] + bias;
      }
    }
  }
}

// ---------------- fused 2-layer persistent LSTM, layer-pipelined ----------------
// 192 WGs: wg<64 run layer 0 (A = Wi@x+bi+bh precomputed); wg>=64 run layer 1
// (Wi1@h0_t + Wh1@h1_{t-1} + biases fused, 1-step pipeline skew behind layer 0).
// All h exchange via write-once tagged streams s0/s1: slot [t][col] holds
// {tag=t+1 (hi32), h bits (lo32)} as a relaxed agent-scope 8B atomic (coherent
// past the non-coherent per-XCD L2s, no cache-maintenance ops, no barriers).
// Write-once => no overwrite hazard; layer 0 free-runs ahead of layer 1.
__global__ __launch_bounds__(RECT, 2) void lstm2(
    const float* __restrict__ A,   const float* __restrict__ Wh0,
    const float* __restrict__ Wi1, const float* __restrict__ Wh1,
    const float* __restrict__ bi1, const float* __restrict__ bh1,
    const float* __restrict__ h00, const float* __restrict__ c00,
    const float* __restrict__ h01, const float* __restrict__ c01,
    ull* __restrict__ s0, ull* __restrict__ s1,
    float* __restrict__ hf0, float* __restrict__ cf0,
    float* __restrict__ hf1, float* __restrict__ cf1,
    float* __restrict__ dec_out, int T)
{
  const int tid = threadIdx.x;
  const int wg = blockIdx.x;

  __shared__ float lds_x[HID];
  __shared__ float lds_h[HID];
  __shared__ float lds_g[64];
  __shared__ float lds_c[16];

  if (wg < 64) {
    // ================= layer 0: 16 units/WG, 8 lanes/row =================
    const int lane8 = tid & 7;
    const int rloc = tid >> 3;            // 0..63
    const int jloc = rloc & 15;
    const int gate = rloc >> 4;           // i,f,g,o
    const int grow = gate * HID + wg * 16 + jloc;

    float4 Wr[32];
    {
      const float4* wrow = (const float4*)(Wh0 + (size_t)grow * HID);
#pragma unroll
      for (int i = 0; i < 32; ++i) Wr[i] = wrow[lane8 + i * 8];
    }

    if (tid < 16) lds_c[tid] = c00[wg * 16 + tid];
    if (tid < 256) ((float4*)lds_h)[tid] = ((const float4*)h00)[tid];
    __syncthreads();

    float areg = (lane8 == 0) ? A[grow] : 0.f;    // step-0 preactivation

    for (int t = 0; t < T; ++t) {
      if (t > 0) {
        const ull* hb = s0 + (size_t)(t - 1) * HID;
        ull v0 = __hip_atomic_load(&hb[2 * tid],     __ATOMIC_RELAXED, __HIP_MEMORY_SCOPE_AGENT);
        ull v1 = __hip_atomic_load(&hb[2 * tid + 1], __ATOMIC_RELAXED, __HIP_MEMORY_SCOPE_AGENT);
        while ((unsigned)(v0 >> 32) < (unsigned)t)
          v0 = __hip_atomic_load(&hb[2 * tid],     __ATOMIC_RELAXED, __HIP_MEMORY_SCOPE_AGENT);
        while ((unsigned)(v1 >> 32) < (unsigned)t)
          v1 = __hip_atomic_load(&hb[2 * tid + 1], __ATOMIC_RELAXED, __HIP_MEMORY_SCOPE_AGENT);
        lds_h[2 * tid]     = __uint_as_float((unsigned)v0);
        lds_h[2 * tid + 1] = __uint_as_float((unsigned)v1);
        __syncthreads();
      }

      const float aval = areg;
      if (lane8 == 0 && t + 1 < T) areg = A[(size_t)(t + 1) * GATES + grow];  // prefetch

      float p0 = 0.f, p1 = 0.f, p2 = 0.f, p3 = 0.f;
#pragma unroll
      for (int i = 0; i < 32; ++i) {
        const float4 hv = *(const float4*)&lds_h[(lane8 << 2) + (i << 5)];
        p0 = fmaf(Wr[i].x, hv.x, p0);
        p1 = fmaf(Wr[i].y, hv.y, p1);
        p2 = fmaf(Wr[i].z, hv.z, p2);
        p3 = fmaf(Wr[i].w, hv.w, p3);
      }
      float sum = (p0 + p1) + (p2 + p3);
      sum += __shfl_xor(sum, 1);
      sum += __shfl_xor(sum, 2);
      sum += __shfl_xor(sum, 4);
      if (lane8 == 0) lds_g[rloc] = sum + aval;
      __syncthreads();

      if (tid < 16) {
        const float gi = lds_g[tid];
        const float gf = lds_g[16 + tid];
        const float gg = lds_g[32 + tid];
        const float go = lds_g[48 + tid];
        const float c = sigmoidf_(gf) * lds_c[tid] + sigmoidf_(gi) * tanhf(gg);
        const float h = sigmoidf_(go) * tanhf(c);
        lds_c[tid] = c;
        const int col = wg * 16 + tid;
        const ull pk = ((ull)(unsigned)(t + 1) << 32) | (ull)__float_as_uint(h);
        __hip_atomic_store(&s0[(size_t)t * HID + col], pk,
                           __ATOMIC_RELAXED, __HIP_MEMORY_SCOPE_AGENT);
        if (t == T - 1) {
          if (hf0) hf0[col] = h;
          if (cf0) cf0[col] = c;
        }
      }
      // no trailing barrier: next iteration's post-staging barrier orders reuse
    }
  } else {
    // ================= layer 1: 8 units/WG, 16 lanes/row, fused Wi+Wh ====
    const int wg1 = wg - 64;              // 0..127
    const int lane16 = tid & 15;
    const int rloc = tid >> 4;            // 0..31
    const int jloc = rloc & 7;
    const int gate = rloc >> 3;
    const int grow = gate * HID + wg1 * 8 + jloc;

    float4 Wir[16], Whr[16];
    {
      const float4* wi = (const float4*)(Wi1 + (size_t)grow * HID);
      const float4* wh = (const float4*)(Wh1 + (size_t)grow * HID);
#pragma unroll
      for (int i = 0; i < 16; ++i) {
        Wir[i] = wi[lane16 + i * 16];
        Whr[i] = wh[lane16 + i * 16];
      }
    }
    const float breg = bi1[grow] + bh1[grow];

    if (tid < 8) lds_c[tid] = c01[wg1 * 8 + tid];
    if (tid < 256) ((float4*)lds_h)[tid] = ((const float4*)h01)[tid];
    __syncthreads();

    for (int t = 0; t < T; ++t) {
      if (t > 0) {
        const ull* hb = s1 + (size_t)(t - 1) * HID;
        ull v0 = __hip_atomic_load(&hb[2 * tid],     __ATOMIC_RELAXED, __HIP_MEMORY_SCOPE_AGENT);
        ull v1 = __hip_atomic_load(&hb[2 * tid + 1], __ATOMIC_RELAXED, __HIP_MEMORY_SCOPE_AGENT);
        while ((unsigned)(v0 >> 32) < (unsigned)t)
          v0 = __hip_atomic_load(&hb[2 * tid],     __ATOMIC_RELAXED, __HIP_MEMORY_SCOPE_AGENT);
        while ((unsigned)(v1 >> 32) < (unsigned)t)
          v1 = __hip_atomic_load(&hb[2 * tid + 1], __ATOMIC_RELAXED, __HIP_MEMORY_SCOPE_AGENT);
        lds_h[2 * tid]     = __uint_as_float((unsigned)v0);
        lds_h[2 * tid + 1] = __uint_as_float((unsigned)v1);
      }
      {
        const ull* xb = s0 + (size_t)t * HID;
        ull v0 = __hip_atomic_load(&xb[2 * tid],     __ATOMIC_RELAXED, __HIP_MEMORY_SCOPE_AGENT);
        ull v1 = __hip_atomic_load(&xb[2 * tid + 1], __ATOMIC_RELAXED, __HIP_MEMORY_SCOPE_AGENT);
        while ((unsigned)(v0 >> 32) < (unsigned)(t + 1))
          v0 = __hip_atomic_load(&xb[2 * tid],     __ATOMIC_RELAXED, __HIP_MEMORY_SCOPE_AGENT);
        while ((unsigned)(v1 >> 32) < (unsigned)(t + 1))
          v1 = __hip_atomic_load(&xb[2 * tid + 1], __ATOMIC_RELAXED, __HIP_MEMORY_SCOPE_AGENT);
        lds_x[2 * tid]     = __uint_as_float((unsigned)v0);
        lds_x[2 * tid + 1] = __uint_as_float((unsigned)v1);
      }
      __syncthreads();

      float p0 = 0.f, p1 = 0.f, p2 = 0.f, p3 = 0.f;
#pragma unroll
      for (int i = 0; i < 16; ++i) {
        const float4 hv = *(const float4*)&lds_h[(lane16 << 2) + (i << 6)];
        p0 = fmaf(Whr[i].x, hv.x, p0);
        p1 = fmaf(Whr[i].y, hv.y, p1);
        p2 = fmaf(Whr[i].z, hv.z, p2);
        p3 = fmaf(Whr[i].w, hv.w, p3);
      }
#pragma unroll
      for (int i = 0; i < 16; ++i) {
        const float4 xv = *(const float4*)&lds_x[(lane16 << 2) + (i << 6)];
        p0 = fmaf(Wir[i].x, xv.x, p0);
        p1 = fmaf(Wir[i].y, xv.y, p1);
        p2 = fmaf(Wir[i].z, xv.z, p2);
        p3 = fmaf(Wir[i].w, xv.w, p3);
      }
      float sum = (p0 + p1) + (p2 + p3);
      sum += __shfl_xor(sum, 1);
      sum += __shfl_xor(sum, 2);
      sum += __shfl_xor(sum, 4);
      sum += __shfl_xor(sum, 8);
      if (lane16 == 0) lds_g[rloc] = sum + breg;
      __syncthreads();

      if (tid < 8) {
        const float gi = lds_g[tid];
        const float gf = lds_g[8 + tid];
        const float gg = lds_g[16 + tid];
        const float go = lds_g[24 + tid];
        const float c = sigmoidf_(gf) * lds_c[tid] + sigmoidf_(gi) * tanhf(gg);
        const float h = sigmoidf_(go) * tanhf(c);
        lds_c[tid] = c;
        const int col = wg1 * 8 + tid;
        const ull pk = ((ull)(unsigned)(t + 1) << 32) | (ull)__float_as_uint(h);
        __hip_atomic_store(&s1[(size_t)t * HID + col], pk,
                           __ATOMIC_RELAXED, __HIP_MEMORY_SCOPE_AGENT);
        if (dec_out) dec_out[(size_t)t * HID + col] = h;
        if (t == T - 1) {
          if (hf1) hf1[col] = h;
          if (cf1) cf1[col] = c;
        }
      }
    }
  }
}

// ---------------- launch ----------------
extern "C" void kernel_launch(void* const* d_in, const int* in_sizes, int n_in,
                              void* d_out, int out_size, void* d_ws, size_t ws_size,
                              hipStream_t stream) {
  const int*   inputs  = (const int*)d_in[0];
  const int*   outputs = (const int*)d_in[1];
  const int*   sos     = (const int*)d_in[2];
  const float* enc_emb = (const float*)d_in[3];
  const float* dec_emb = (const float*)d_in[4];
  const float* enc_Wih = (const float*)d_in[5];
  const float* enc_Whh = (const float*)d_in[6];
  const float* enc_bih = (const float*)d_in[7];
  const float* enc_bhh = (const float*)d_in[8];
  const float* dec_Wih = (const float*)d_in[9];
  const float* dec_Whh = (const float*)d_in[10];
  const float* dec_bih = (const float*)d_in[11];
  const float* dec_bhh = (const float*)d_in[12];
  const float* lin_W   = (const float*)d_in[13];
  const float* lin_b   = (const float*)d_in[14];

  float* out = (float*)d_out;
  // d_out scratch carve (all consumed before the logits GEMM writes):
  //   A_enc  @ float 0        (2048*4096)
  //   A_dec  @ float 8388608  (2048*4096)
  //   4 tagged streams (ull[2048*1024] each) @ float 16777216
  float* A_enc = out;
  float* A_dec = out + 8388608;
  ull*   s0e   = (ull*)(out + 16777216);
  ull*   s1e   = s0e + 2097152;
  ull*   s0d   = s1e + 2097152;
  ull*   s1d   = s0d + 2097152;

  char* ws = (char*)d_ws;
  float* zerosv = (float*)(ws + 0);       // 1024 zeros
  float* hf0    = (float*)(ws + 4096);
  float* cf0    = (float*)(ws + 8192);
  float* hf1    = (float*)(ws + 12288);
  float* cf1    = (float*)(ws + 16384);
  int*   dtoks  = (int*)(ws + 20480);     // 2048 decoder tokens
  float* B1 = (float*)(ws + ((size_t)1  << 20));  // 8 MB: enc embeddings
  float* B3 = (float*)(ws + ((size_t)10 << 20));  // 8 MB: dec embeddings
  float* B2 = (float*)(ws + ((size_t)19 << 20));  // 8 MB: dec_out (logits GEMM X)

  const size_t WOFF = (size_t)GATES * HID;  // layer stride in Wih/Whh
  const dim3 gemm_blk(256);
  const dim3 gemmA_grid(GATES / 64, S_LEN / 64);
  const dim3 gemmV_grid((VOCAB + 63) / 64, T_LEN / 64);

  // zero stream tags (4 x 16 MB in d_out) + zeros vector
  zero_f4<<<2048, 256, 0, stream>>>((float4*)(out + 16777216), 4194304);
  zero_f32<<<4, 256, 0, stream>>>(zerosv, 1024);
  build_dec_tokens<<<8, 256, 0, stream>>>(outputs, sos, dtoks, T_LEN);

  // embeddings + layer-0 preactivation GEMMs (both precomputable: teacher forcing)
  gather_rows<<<S_LEN, 256, 0, stream>>>(enc_emb, inputs, B1);
  gemm_xwt<<<gemmA_grid, gemm_blk, 0, stream>>>(B1, enc_Wih, enc_bih, enc_bhh, A_enc, S_LEN, GATES, HID);
  gather_rows<<<T_LEN, 256, 0, stream>>>(dec_emb, dtoks, B3);
  gemm_xwt<<<gemmA_grid, gemm_blk, 0, stream>>>(B3, dec_Wih, dec_bih, dec_bhh, A_dec, T_LEN, GATES, HID);

  // encoder: both layers pipelined in one kernel
  lstm2<<<NWG2, RECT, 0, stream>>>(
      A_enc, enc_Whh, enc_Wih + WOFF, enc_Whh + WOFF, enc_bih + GATES, enc_bhh + GATES,
      zerosv, zerosv, zerosv, zerosv, s0e, s1e, hf0, cf0, hf1, cf1, nullptr, S_LEN);

  // decoder: both layers pipelined; layer-1 h-stream also written plain to B2
  lstm2<<<NWG2, RECT, 0, stream>>>(
      A_dec, dec_Whh, dec_Wih + WOFF, dec_Whh + WOFF, dec_bih + GATES, dec_bhh + GATES,
      hf0, cf0, hf1, cf1, s0d, s1d, nullptr, nullptr, nullptr, nullptr, B2, T_LEN);

  // logits
  gemm_xwt<<<gemmV_grid, gemm_blk, 0, stream>>>(B2, lin_W, lin_b, nullptr, out, T_LEN, VOCAB, HID);
}